// Round 8
// baseline (141.622 us; speedup 1.0000x reference)
//
#include <hip/hip_runtime.h>

// Signature-kernel MMD via Goursat PDE — round 9.
// Round-8 postmortem: LDS-staging dX bought 1.5us (92.1us, VALUBusy 72%)
// -> scalar-path theory wrong. Remaining in-loop memory op: per-row ya/yb
// reload. Its GEOMETRY is the cost: lane l reads rows 2l,2l+1 -> 128B
// per-lane stride -> each load gathers ~64 cache lines, working set 256KB/CU
// >> L1 -> strided L2 gathers every row = the ~28% non-issue gap.
// Round-9: FRAGMENT LAYOUT in ws. sig_diff writes dInc as
// frag[path][half=r&1][quad][lane=r>>1] (float4), so:
//  - ya[q]/yb[q] reloads become lane-CONSECUTIVE global_load_dwordx4
//    (1KB/instr, imm offsets off one per-lane base, L2-friendly);
//  - A-path LDS staging copies frag verbatim (coalesced read, conflict-free
//    write); in-loop row reads are broadcast ds_read_b128 at imm offsets,
//    unroll-2 turns the half-select into compile-time offsets.
// Arithmetic order identical to r8. No pins, no rings (lessons r3/r6/r7).

#define XY_BLOCKS 1024
#define TRI_BLOCKS 544
#define NBT (XY_BLOCKS + 2 * TRI_BLOCKS)        // 2112 blocks
#define FRAG_MAT 32768                          // float4 per matrix frag
// frag idx = mat*32768 + path*512 + (r&1)*256 + q*64 + (r>>1)

template <int C, int RM, int BM, bool BC>
__device__ __forceinline__ float dpp0(float x) {
    return __builtin_bit_cast(float, __builtin_amdgcn_update_dpp(
        0, __builtin_bit_cast(int, x), C, RM, BM, BC));
}

// 64-lane inclusive prefix sum, pure VALU (6 dependent adds).
__device__ __forceinline__ float wave_scan_incl(float v) {
    v += dpp0<0x111, 0xf, 0xf, true>(v);   // row_shr:1
    v += dpp0<0x112, 0xf, 0xf, true>(v);   // row_shr:2
    v += dpp0<0x114, 0xf, 0xf, true>(v);   // row_shr:4
    v += dpp0<0x118, 0xf, 0xf, true>(v);   // row_shr:8
    v += dpp0<0x142, 0xa, 0xf, false>(v);  // row_bcast:15 -> rows 1,3
    v += dpp0<0x143, 0xc, 0xf, false>(v);  // row_bcast:31 -> rows 2,3
    return v;
}

// lane l gets lane l-1's x; lane 0 gets `oldv`.
__device__ __forceinline__ float wave_shr1(float x, float oldv) {
    return __builtin_bit_cast(float, __builtin_amdgcn_update_dpp(
        __builtin_bit_cast(int, oldv), __builtin_bit_cast(int, x),
        0x138, 0xf, 0xf, false));          // wave_shr:1
}

// ---- kernel 1: path increments -> FRAGMENT layout in ws ----
// block 254 zeroes the (half=1, lane=63) pad slots; block 0 zeroes out[0].
__global__ __launch_bounds__(256) void sig_diff(
    const float* __restrict__ X, const float* __restrict__ Y,
    float* __restrict__ dInc, float* __restrict__ out)
{
    float4* F = (float4*)dInc;
    if (blockIdx.x == 254) {               // zero pad slots (row-127 yb)
        int t = threadIdx.x;
#pragma unroll
        for (int s = 0; s < 2; ++s, t += 256) {
            int mat = t >> 8, rem = t & 255;
            int path = rem >> 2, q = rem & 3;
            F[mat * FRAG_MAT + path * 512 + 256 + q * 64 + 63] =
                make_float4(0.f, 0.f, 0.f, 0.f);
        }
        return;
    }
    if (blockIdx.x == 0 && threadIdx.x == 0) out[0] = 0.0f;
    int i = blockIdx.x * 256 + threadIdx.x;   // work id, 65024 total
    int which = (i >= 32512) ? 1 : 0;
    int j = i - which * 32512;
    int a = j / 508;                          // 127*4 float4 per path
    int rq = j - a * 508;                     // r*4 + q
    int r = rq >> 2, q = rq & 3;
    const float* S = which ? Y : X;
    const float4* p = (const float4*)(S + a * 2048) + rq;
    float4 v0 = p[0], v1 = p[4];              // +16 floats = next row
    float4 d;
    d.x = v1.x - v0.x; d.y = v1.y - v0.y;
    d.z = v1.z - v0.z; d.w = v1.w - v0.w;
    F[which * FRAG_MAT + a * 512 + (r & 1) * 256 + q * 64 + (r >> 1)] = d;
}

// ---- kernel 2: PDE. 2112 blocks * 4 waves, one (g,a,b0) per block. ----
__global__ __launch_bounds__(256, 8) void sig_pde9(
    const float* __restrict__ dInc, float* __restrict__ out)
{
    __shared__ float4 Xs4[512];            // A-path in FRAG layout (8 KB)
    __shared__ float red[4];
    const int wid  = threadIdx.x >> 6;
    const int lane = threadIdx.x & 63;
    const int BT   = blockIdx.x;

    // block-uniform decode -> (gram g, a, b0); b = b0 + wave id
    int g, a, b0;
    if (BT < XY_BLOCKS) {                  // XY: dense 64x64
        g = 2; a = BT >> 4; b0 = (BT & 15) << 2;
    } else {                               // XX / YY upper triangles
        int t = BT - XY_BLOCKS; g = 0;
        if (t >= TRI_BLOCKS) { t -= TRI_BLOCKS; g = 1; }
        int aa = 0;
        for (;;) { int nb = (67 - aa) >> 2; if (t < nb) break; t -= nb; ++aa; }
        a = aa; b0 = aa + (t << 2);
    }
    const int b = b0 + wid;

    const float4* F  = (const float4*)dInc;
    const float4* Af = F + ((g == 1) ? FRAG_MAT : 0) + a * 512;  // row path
    const float4* Bf = F + ((g == 0) ? 0 : FRAG_MAT) + b * 512;  // col path

    // stage the block-uniform A-path frag into LDS verbatim:
    // coalesced global read, conflict-free LDS write, broadcast reads later.
    {
        const int tid = threadIdx.x;
        Xs4[tid]       = Af[tid];
        Xs4[tid + 256] = Af[tid + 256];
    }
    __syncthreads();

    float acc = 0.0f;
    if (g == 2 || b <= 63) {               // dead triangle waves skip compute
        const float weight = (g == 2) ? (-2.0f / 4096.0f)
                                      : ((a == b ? 1.0f : 2.0f) / 4096.0f);

        // per-lane dY fragments: lane-consecutive float4 loads (coalesced).
        // Not pinned — if the compiler reloads these in-loop, the reloads
        // are now 1KB/instr coalesced instead of 64-line gathers.
        float4 ya0 = Bf[       lane], ya1 = Bf[ 64 + lane],
               ya2 = Bf[128 + lane], ya3 = Bf[192 + lane];
        float4 yb0 = Bf[256 + lane], yb1 = Bf[320 + lane],
               yb2 = Bf[384 + lane], yb3 = Bf[448 + lane];

        float g_lo = 1.0f, g_hi = 1.0f;    // G[r][2l+1], G[r][2l+2]
        const bool last = (lane == 63);

#define SIG_ROW(x0,x1,x2,x3)                                                \
        {                                                                   \
            float s0=-0.5f, s1=-0.5f, t0=-0.5f, t1=-0.5f;                   \
            s0=fmaf(x0.x,ya0.x,s0); s1=fmaf(x0.y,ya0.y,s1);                 \
            t0=fmaf(x0.x,yb0.x,t0); t1=fmaf(x0.y,yb0.y,t1);                 \
            s0=fmaf(x0.z,ya0.z,s0); s1=fmaf(x0.w,ya0.w,s1);                 \
            t0=fmaf(x0.z,yb0.z,t0); t1=fmaf(x0.w,yb0.w,t1);                 \
            s0=fmaf(x1.x,ya1.x,s0); s1=fmaf(x1.y,ya1.y,s1);                 \
            t0=fmaf(x1.x,yb1.x,t0); t1=fmaf(x1.y,yb1.y,t1);                 \
            s0=fmaf(x1.z,ya1.z,s0); s1=fmaf(x1.w,ya1.w,s1);                 \
            t0=fmaf(x1.z,yb1.z,t0); t1=fmaf(x1.w,yb1.w,t1);                 \
            s0=fmaf(x2.x,ya2.x,s0); s1=fmaf(x2.y,ya2.y,s1);                 \
            t0=fmaf(x2.x,yb2.x,t0); t1=fmaf(x2.y,yb2.y,t1);                 \
            s0=fmaf(x2.z,ya2.z,s0); s1=fmaf(x2.w,ya2.w,s1);                 \
            t0=fmaf(x2.z,yb2.z,t0); t1=fmaf(x2.w,yb2.w,t1);                 \
            s0=fmaf(x3.x,ya3.x,s0); s1=fmaf(x3.y,ya3.y,s1);                 \
            t0=fmaf(x3.x,yb3.x,t0); t1=fmaf(x3.y,yb3.y,t1);                 \
            s0=fmaf(x3.z,ya3.z,s0); s1=fmaf(x3.w,ya3.w,s1);                 \
            t0=fmaf(x3.z,yb3.z,t0); t1=fmaf(x3.w,yb3.w,t1);                 \
            const float i0 = s0 + s1;          /* inc(r, 2l)   - 1 */       \
            const float i1 = t0 + t1;          /* inc(r, 2l+1) - 1 */       \
            const float gl = wave_shr1(g_hi, 1.0f);  /* G[r][2l] */         \
            const float c0 = fmaf(gl, i0, g_lo);                            \
            const float c1 = last ? 0.0f : fmaf(g_lo, i1, g_hi);            \
            const float S  = wave_scan_incl(c0 + c1);                       \
            g_lo = (S - c1) + 1.0f;                                         \
            g_hi = S + 1.0f;                                                \
        }

        // rows 0..125 as (even,odd) pairs: frag offsets are compile-time
        // imm per half; broadcast ds_read_b128, conflict-free.
#pragma unroll 1
        for (int k = 0; k < 63; ++k) {
            const float4* rp = &Xs4[k];
            {   // row 2k   (half 0)
                float4 x0 = rp[0],   x1 = rp[64],  x2 = rp[128], x3 = rp[192];
                SIG_ROW(x0, x1, x2, x3)
            }
            {   // row 2k+1 (half 1)
                float4 x0 = rp[256], x1 = rp[320], x2 = rp[384], x3 = rp[448];
                SIG_ROW(x0, x1, x2, x3)
            }
        }
        {   // row 126 (half 0, l=63)
            const float4* rp = &Xs4[63];
            float4 x0 = rp[0], x1 = rp[64], x2 = rp[128], x3 = rp[192];
            SIG_ROW(x0, x1, x2, x3)
        }
#undef SIG_ROW

        const float kab = __builtin_bit_cast(float,
            __builtin_amdgcn_readlane(__builtin_bit_cast(int, g_lo), 63));
        acc = weight * kab;
    }

    // fused reduction: 4 waves -> LDS -> one atomic per block
    if (lane == 0) red[wid] = acc;
    __syncthreads();
    if (threadIdx.x == 0)
        atomicAdd(out, (red[0] + red[1]) + (red[2] + red[3]));
}

__global__ __launch_bounds__(256) void sig_reduce2(
    const float* __restrict__ v, float* __restrict__ out, int n)
{
    __shared__ float red[256];
    float s = 0.0f;
    for (int i = threadIdx.x; i < n; i += 256) s += v[i];
    red[threadIdx.x] = s;
    __syncthreads();
    for (int st = 128; st > 0; st >>= 1) {
        if (threadIdx.x < st) red[threadIdx.x] += red[threadIdx.x + st];
        __syncthreads();
    }
    if (threadIdx.x == 0) out[0] = red[0];
}

// ---- fallback (ws too small for increment staging): round-1 kernel ----
__global__ __launch_bounds__(64) void sig_pde_kernel(
    const float* __restrict__ X, const float* __restrict__ Y,
    float* __restrict__ ws)
{
    __shared__ float Xs[2048];
    const int T = blockIdx.x;
    const int g = T >> 12;
    const int t = T & 4095;
    const int a = t >> 6, b = t & 63;
    const int lane = threadIdx.x;
    if (g < 2 && a > b) { if (lane == 0) ws[T] = 0.0f; return; }
    const float* P = (g == 1) ? Y : X;
    const float* Q = (g == 0) ? X : Y;
    const float weight = (g == 2) ? (-2.0f / 4096.0f)
                                  : ((a == b ? 1.0f : 2.0f) / 4096.0f);
    {
        const float4* Pa = (const float4*)(P + a * 2048);
        float4* Xs4 = (float4*)Xs;
#pragma unroll
        for (int k = 0; k < 8; ++k) Xs4[lane + (k << 6)] = Pa[lane + (k << 6)];
    }
    __syncthreads();
    {
        float tmp[32];
#pragma unroll
        for (int k = 0; k < 32; ++k) {
            int idx = lane + (k << 6);
            tmp[k] = (idx < 2032) ? (Xs[idx + 16] - Xs[idx]) : 0.0f;
        }
        __syncthreads();
#pragma unroll
        for (int k = 0; k < 32; ++k) {
            int idx = lane + (k << 6);
            if (idx < 2032) Xs[idx] = tmp[k];
        }
    }
    __syncthreads();
    float y0[16], y1[16];
    {
        const float* Qb = Q + b * 2048;
        const int r0 = lane << 1;
        const int r2 = (r0 + 2 > 127) ? 127 : (r0 + 2);
        const float4* A4 = (const float4*)(Qb + r0 * 16);
        const float4* B4 = (const float4*)(Qb + (r0 + 1) * 16);
        const float4* C4 = (const float4*)(Qb + r2 * 16);
#pragma unroll
        for (int q = 0; q < 4; ++q) {
            float4 ra = A4[q], rb = B4[q], rc = C4[q];
            y0[4*q+0] = rb.x - ra.x;  y1[4*q+0] = rc.x - rb.x;
            y0[4*q+1] = rb.y - ra.y;  y1[4*q+1] = rc.y - rb.y;
            y0[4*q+2] = rb.z - ra.z;  y1[4*q+2] = rc.z - rb.z;
            y0[4*q+3] = rb.w - ra.w;  y1[4*q+3] = rc.w - rb.w;
        }
    }
    float g_lo = 1.0f, g_hi = 1.0f;
    const bool last = (lane == 63);
    for (int r = 0; r < 127; ++r) {
        const float* xrow = Xs + r * 16;
        float s0 = -0.5f, s1 = -0.5f, t0 = -0.5f, t1 = -0.5f;
#pragma unroll
        for (int d = 0; d < 16; d += 2) {
            s0 = fmaf(xrow[d], y0[d], s0);   s1 = fmaf(xrow[d+1], y0[d+1], s1);
            t0 = fmaf(xrow[d], y1[d], t0);   t1 = fmaf(xrow[d+1], y1[d+1], t1);
        }
        const float i0 = s0 + s1, i1 = t0 + t1;
        const float gl = wave_shr1(g_hi, 1.0f);
        const float c0 = fmaf(gl, i0, g_lo);
        const float c1 = last ? 0.0f : fmaf(g_lo, i1, g_hi);
        const float S = wave_scan_incl(c0 + c1);
        g_lo = (S - c1) + 1.0f;
        g_hi = S + 1.0f;
    }
    const float kab = __builtin_bit_cast(float,
        __builtin_amdgcn_readlane(__builtin_bit_cast(int, g_lo), 63));
    if (lane == 0) ws[T] = weight * kab;
}

extern "C" void kernel_launch(void* const* d_in, const int* in_sizes, int n_in,
                              void* d_out, int out_size, void* d_ws, size_t ws_size,
                              hipStream_t stream) {
    const float* X = (const float*)d_in[0];
    const float* Y = (const float*)d_in[1];
    float* out = (float*)d_out;
    float* ws  = (float*)d_ws;

    const size_t need = (size_t)(2 * FRAG_MAT) * sizeof(float4);  // 1 MiB
    if (ws_size >= need) {
        sig_diff<<<255, 256, 0, stream>>>(X, Y, ws, out);
        sig_pde9<<<NBT, 256, 0, stream>>>(ws, out);
    } else {
        sig_pde_kernel<<<12288, 64, 0, stream>>>(X, Y, ws);
        sig_reduce2<<<1, 256, 0, stream>>>(ws, out, 12288);
    }
}